// Round 2
// baseline (2186.419 us; speedup 1.0000x reference)
//
#include <hip/hip_runtime.h>
#include <math.h>

// EdgeEvidenceHead fused kernel — round 2: conflict-free LDS layout.
//
// Round-1 post-mortem: 2.52 ms, VALUBusy 55.6%, SQ_LDS_BANK_CONFLICT 3.2e8.
//   (a) transposed gather writes hit 2 banks (stride 144 ≡ 16 mod 32) -> 16-way
//   (b) B-reads at 32B lane stride -> 8-way
// Fix: natural [edge][feat] layout (gather writes = consecutive float4,
// conflict-free), A-fragments via broadcast ds_read_b32 (2 addrs/wave, free),
// column ownership = two float4 blocks (tn*4, 128+tn*4) so B-reads are the
// standard consecutive-16B pattern. K-chunks fully unrolled -> LDS reads use
// offset immediates, inner loop is pure v_fma_f32 (32/k/lane).

#define HIDDEN   128
#define EHID     256
#define NEDGES   500000
#define MT       32      // edges per block
#define KT       32      // K chunk
#define STRZ     132     // zu/zv row stride (floats), +4 pad
#define STRA     36      // ach row stride (floats)
#define NTHREADS 256

__device__ __forceinline__ float softplus_f(float x) {
    return fmaxf(x, 0.0f) + log1pf(expf(-fabsf(x)));
}

__global__ __launch_bounds__(NTHREADS, 2)
void edge_evidence_kernel(const float* __restrict__ z,
                          const int*   __restrict__ eidx,
                          const float* __restrict__ extra,
                          const float* __restrict__ W1,
                          const float* __restrict__ b1,
                          const float* __restrict__ W2,
                          const float* __restrict__ b2,
                          float* __restrict__ out)
{
    __shared__ float zu[MT][STRZ];    // 16896 B
    __shared__ float zv[MT][STRZ];    // 16896 B
    __shared__ float ach[MT][STRA];   //  4608 B  (abs/prod/tail A-chunks)
    __shared__ float Bch[KT][EHID];   // 32768 B
    __shared__ int   su[MT], sv[MT];
    __shared__ float sdot[MT], scos[MT];

    const int t  = threadIdx.x;
    const int e0 = blockIdx.x * MT;
    const int tn = t & 31;   // owns cols [tn*4, tn*4+4) and [128+tn*4, 128+tn*4+4)
    const int tm = t >> 5;   // owns edges [tm*4, tm*4+4)

    if (t < MT)          su[t]      = eidx[e0 + t];
    else if (t < 2 * MT) sv[t - MT] = eidx[NEDGES + e0 + (t - MT)];
    __syncthreads();

    // ---- gather z_u/z_v (natural layout) + fused dot/norm/cos ----
    // 32 consecutive lanes cover one edge's 128 dims (one float4 each):
    // writes are consecutive float4s in one row -> conflict-free.
    {
        const int c4 = t & 31;
        const int eb = t >> 5;
        for (int r = 0; r < 4; ++r) {
            const int e = eb + 8 * r;
            const float4 a = *reinterpret_cast<const float4*>(&z[(size_t)su[e] * HIDDEN + c4 * 4]);
            const float4 b = *reinterpret_cast<const float4*>(&z[(size_t)sv[e] * HIDDEN + c4 * 4]);
            *reinterpret_cast<float4*>(&zu[e][c4 * 4]) = a;
            *reinterpret_cast<float4*>(&zv[e][c4 * 4]) = b;
            float d  = a.x*b.x + a.y*b.y + a.z*b.z + a.w*b.w;
            float nu = a.x*a.x + a.y*a.y + a.z*a.z + a.w*a.w;
            float nv = b.x*b.x + b.y*b.y + b.z*b.z + b.w*b.w;
            #pragma unroll
            for (int m = 16; m >= 1; m >>= 1) {
                d  += __shfl_xor(d,  m);
                nu += __shfl_xor(nu, m);
                nv += __shfl_xor(nv, m);
            }
            if (c4 == 0) {
                sdot[e] = d;
                const float nn = fmaxf(sqrtf(nu), 1e-12f) * fmaxf(sqrtf(nv), 1e-12f);
                scos[e] = d / nn;
            }
        }
    }

    float acc[4][8];
    #pragma unroll
    for (int i = 0; i < 4; ++i)
        #pragma unroll
        for (int j = 0; j < 8; ++j) acc[i][j] = 0.0f;

    // ---- K loop: 16 chunks of 32 + tail of 7 (dot, cos, extra[5]) ----
    for (int kc = 0; kc < 17; ++kc) {
        const int kbase = kc * KT;
        const int krows = (kc == 16) ? 7 : KT;

        __syncthreads();   // previous chunk's readers done

        // stage W1 chunk -> Bch: 64 consecutive float4 per wave row -> conflict-free
        for (int i = t; i < krows * (EHID / 4); i += NTHREADS) {
            const int kk = i >> 6;
            const int c  = i & 63;
            *reinterpret_cast<float4*>(&Bch[kk][c * 4]) =
                *reinterpret_cast<const float4*>(&W1[(size_t)(kbase + kk) * EHID + c * 4]);
        }

        // select/stage A chunk (natural [edge][k] layout)
        const float* abase;
        int astr;
        if (kc < 4) {
            abase = &zu[0][kbase];            astr = STRZ;
        } else if (kc < 8) {
            abase = &zv[0][kbase - 128];      astr = STRZ;
        } else if (kc < 16) {
            const int off = (kc < 12) ? (kbase - 256) : (kbase - 384);
            const bool isabs = (kc < 12);
            for (int i = t; i < KT * MT; i += NTHREADS) {
                const int e = i >> 5, kk = i & 31;   // 32 lanes: same row, consecutive kk
                const float xu = zu[e][off + kk];
                const float xv = zv[e][off + kk];
                ach[e][kk] = isabs ? fabsf(xu - xv) : (xu * xv);
            }
            abase = &ach[0][0];               astr = STRA;
        } else {
            if (t < MT) { ach[t][0] = sdot[t]; ach[t][1] = scos[t]; }
            for (int i = t; i < MT * 5; i += NTHREADS) {
                const int e = i / 5, x = i % 5;
                ach[e][2 + x] = extra[(size_t)(e0 + e) * 5 + x];
            }
            abase = &ach[0][0];               astr = STRA;
        }

        __syncthreads();

        const float* arow0 = abase + (tm * 4 + 0) * astr;
        const float* arow1 = abase + (tm * 4 + 1) * astr;
        const float* arow2 = abase + (tm * 4 + 2) * astr;
        const float* arow3 = abase + (tm * 4 + 3) * astr;
        const float* bbase = &Bch[0][tn * 4];

        // ---- inner loop: A = broadcast ds_read_b32 (offset-immediate),
        //      B = 2x conflict-free ds_read_b128, 32 v_fma_f32 per k ----
        if (krows == KT) {
            #pragma unroll
            for (int k = 0; k < KT; ++k) {
                const float a0 = arow0[k], a1 = arow1[k], a2 = arow2[k], a3 = arow3[k];
                const float4 bl = *reinterpret_cast<const float4*>(bbase + k * EHID);
                const float4 bh = *reinterpret_cast<const float4*>(bbase + k * EHID + 128);
                acc[0][0] = fmaf(a0, bl.x, acc[0][0]); acc[0][1] = fmaf(a0, bl.y, acc[0][1]);
                acc[0][2] = fmaf(a0, bl.z, acc[0][2]); acc[0][3] = fmaf(a0, bl.w, acc[0][3]);
                acc[0][4] = fmaf(a0, bh.x, acc[0][4]); acc[0][5] = fmaf(a0, bh.y, acc[0][5]);
                acc[0][6] = fmaf(a0, bh.z, acc[0][6]); acc[0][7] = fmaf(a0, bh.w, acc[0][7]);
                acc[1][0] = fmaf(a1, bl.x, acc[1][0]); acc[1][1] = fmaf(a1, bl.y, acc[1][1]);
                acc[1][2] = fmaf(a1, bl.z, acc[1][2]); acc[1][3] = fmaf(a1, bl.w, acc[1][3]);
                acc[1][4] = fmaf(a1, bh.x, acc[1][4]); acc[1][5] = fmaf(a1, bh.y, acc[1][5]);
                acc[1][6] = fmaf(a1, bh.z, acc[1][6]); acc[1][7] = fmaf(a1, bh.w, acc[1][7]);
                acc[2][0] = fmaf(a2, bl.x, acc[2][0]); acc[2][1] = fmaf(a2, bl.y, acc[2][1]);
                acc[2][2] = fmaf(a2, bl.z, acc[2][2]); acc[2][3] = fmaf(a2, bl.w, acc[2][3]);
                acc[2][4] = fmaf(a2, bh.x, acc[2][4]); acc[2][5] = fmaf(a2, bh.y, acc[2][5]);
                acc[2][6] = fmaf(a2, bh.z, acc[2][6]); acc[2][7] = fmaf(a2, bh.w, acc[2][7]);
                acc[3][0] = fmaf(a3, bl.x, acc[3][0]); acc[3][1] = fmaf(a3, bl.y, acc[3][1]);
                acc[3][2] = fmaf(a3, bl.z, acc[3][2]); acc[3][3] = fmaf(a3, bl.w, acc[3][3]);
                acc[3][4] = fmaf(a3, bh.x, acc[3][4]); acc[3][5] = fmaf(a3, bh.y, acc[3][5]);
                acc[3][6] = fmaf(a3, bh.z, acc[3][6]); acc[3][7] = fmaf(a3, bh.w, acc[3][7]);
            }
        } else {
            #pragma unroll
            for (int k = 0; k < 7; ++k) {
                const float a0 = arow0[k], a1 = arow1[k], a2 = arow2[k], a3 = arow3[k];
                const float4 bl = *reinterpret_cast<const float4*>(bbase + k * EHID);
                const float4 bh = *reinterpret_cast<const float4*>(bbase + k * EHID + 128);
                acc[0][0] = fmaf(a0, bl.x, acc[0][0]); acc[0][1] = fmaf(a0, bl.y, acc[0][1]);
                acc[0][2] = fmaf(a0, bl.z, acc[0][2]); acc[0][3] = fmaf(a0, bl.w, acc[0][3]);
                acc[0][4] = fmaf(a0, bh.x, acc[0][4]); acc[0][5] = fmaf(a0, bh.y, acc[0][5]);
                acc[0][6] = fmaf(a0, bh.z, acc[0][6]); acc[0][7] = fmaf(a0, bh.w, acc[0][7]);
                acc[1][0] = fmaf(a1, bl.x, acc[1][0]); acc[1][1] = fmaf(a1, bl.y, acc[1][1]);
                acc[1][2] = fmaf(a1, bl.z, acc[1][2]); acc[1][3] = fmaf(a1, bl.w, acc[1][3]);
                acc[1][4] = fmaf(a1, bh.x, acc[1][4]); acc[1][5] = fmaf(a1, bh.y, acc[1][5]);
                acc[1][6] = fmaf(a1, bh.z, acc[1][6]); acc[1][7] = fmaf(a1, bh.w, acc[1][7]);
                acc[2][0] = fmaf(a2, bl.x, acc[2][0]); acc[2][1] = fmaf(a2, bl.y, acc[2][1]);
                acc[2][2] = fmaf(a2, bl.z, acc[2][2]); acc[2][3] = fmaf(a2, bl.w, acc[2][3]);
                acc[2][4] = fmaf(a2, bh.x, acc[2][4]); acc[2][5] = fmaf(a2, bh.y, acc[2][5]);
                acc[2][6] = fmaf(a2, bh.z, acc[2][6]); acc[2][7] = fmaf(a2, bh.w, acc[2][7]);
                acc[3][0] = fmaf(a3, bl.x, acc[3][0]); acc[3][1] = fmaf(a3, bl.y, acc[3][1]);
                acc[3][2] = fmaf(a3, bl.z, acc[3][2]); acc[3][3] = fmaf(a3, bl.w, acc[3][3]);
                acc[3][4] = fmaf(a3, bh.x, acc[3][4]); acc[3][5] = fmaf(a3, bh.y, acc[3][5]);
                acc[3][6] = fmaf(a3, bh.z, acc[3][6]); acc[3][7] = fmaf(a3, bh.w, acc[3][7]);
            }
        }
    }

    // ---- epilogue: bias + ReLU, GEMM2 (256->2), softplus ----
    // owned col j: j<4 -> tn*4+j ; j>=4 -> 128+tn*4+(j-4)
    float b1v[8], w2a[8], w2b[8];
    *reinterpret_cast<float4*>(&b1v[0]) = *reinterpret_cast<const float4*>(&b1[tn * 4]);
    *reinterpret_cast<float4*>(&b1v[4]) = *reinterpret_cast<const float4*>(&b1[128 + tn * 4]);
    #pragma unroll
    for (int j = 0; j < 8; ++j) {
        const int col = (j < 4) ? (tn * 4 + j) : (128 + tn * 4 + (j - 4));
        w2a[j] = W2[col * 2 + 0];
        w2b[j] = W2[col * 2 + 1];
    }
    const float bb0 = b2[0], bb1 = b2[1];

    #pragma unroll
    for (int i = 0; i < 4; ++i) {
        float p0 = 0.0f, p1 = 0.0f;
        #pragma unroll
        for (int j = 0; j < 8; ++j) {
            const float h = fmaxf(acc[i][j] + b1v[j], 0.0f);
            p0 = fmaf(h, w2a[j], p0);
            p1 = fmaf(h, w2b[j], p1);
        }
        #pragma unroll
        for (int m = 16; m >= 1; m >>= 1) {
            p0 += __shfl_xor(p0, m);
            p1 += __shfl_xor(p1, m);
        }
        if (tn == 0) {
            const int e = e0 + tm * 4 + i;
            out[(size_t)e * 2 + 0] = softplus_f(p0 + bb0);
            out[(size_t)e * 2 + 1] = softplus_f(p1 + bb1);
        }
    }
}

extern "C" void kernel_launch(void* const* d_in, const int* in_sizes, int n_in,
                              void* d_out, int out_size, void* d_ws, size_t ws_size,
                              hipStream_t stream) {
    const float* z     = (const float*)d_in[0];
    const int*   eidx  = (const int*)  d_in[1];
    const float* extra = (const float*)d_in[2];
    const float* W1    = (const float*)d_in[3];
    const float* b1    = (const float*)d_in[4];
    const float* W2    = (const float*)d_in[5];
    const float* b2    = (const float*)d_in[6];
    float* out = (float*)d_out;

    const int nblocks = NEDGES / MT;   // 15625 exactly
    edge_evidence_kernel<<<dim3(nblocks), dim3(NTHREADS), 0, stream>>>(
        z, eidx, extra, W1, b1, W2, b2, out);
}

// Round 3
// 736.358 us; speedup vs baseline: 2.9692x; 2.9692x over previous
//
#include <hip/hip_runtime.h>
#include <math.h>

// EdgeEvidenceHead — round 3: split-bf16 MFMA (fp32-accurate via 3-product hi/lo).
//
// GEMM1 (500k x 519 @ 519 x 256) on the matrix pipe: x = x_hi + x_lo (bf16 pair),
// A*B ~= Ah*Bh + Al*Bh + Ah*Bl  (error ~2^-17, fp32-like).
// prep kernel: W1 -> ws as pre-swizzled per-chunk LDS byte images (linear
// global_load_lds staging; swizzle baked into source — rule #21).
// main: 64 edges/block, 17 K-chunks, W double-buffered prefetch-1-ahead,
// abs/prod chunks rebuilt per-chunk from resident z hi/lo, 1 block/CU (147KB LDS).

typedef __attribute__((ext_vector_type(8))) short short8;
typedef __attribute__((ext_vector_type(4))) float f32x4;
typedef unsigned int u32;
typedef unsigned short u16;

#define NEDGES 500000
#define MTE    64
#define NBLK   ((NEDGES + MTE - 1) / MTE)   // 7813
#define WCHUNK 32768                         // one K32-chunk W image: hi 16KB + lo 16KB
#define NCH    17                            // 544 = 17 * 32 (519 zero-padded)

// LDS offsets (bytes)
#define OFF_FHI  0        // z features hi: [64 e][256 k] bf16, swizzled  (32KB)
#define OFF_FLO  32768    // z features lo                                 (32KB)
#define OFF_W    65536    // W chunk dbuf: 2 x 32KB (hi 16KB + lo 16KB)    (64KB)
#define OFF_FC   131072   // built-chunk dbuf: 2 x (hi 4KB + lo 4KB)       (16KB)
#define OFF_SU   147456
#define OFF_SV   147712
#define OFF_SDOT 147968
#define OFF_SCOS 148224
#define OFF_SRED 148480   // [4 waves][64 e] float2                        (2KB)
#define LDS_SZ   150528

__device__ __forceinline__ u16 f2bf(float f) {              // RTN-even bf16
    u32 u = __float_as_uint(f);
    return (u16)((u + 0x7fffu + ((u >> 16) & 1u)) >> 16);
}
__device__ __forceinline__ float bf2f(u16 h) { return __uint_as_float(((u32)h) << 16); }
__device__ __forceinline__ float softplus_f(float x) {
    return fmaxf(x, 0.0f) + log1pf(expf(-fabsf(x)));
}
// XOR swizzles: spread row-strided 16B reads across the 8 slot positions
__device__ __forceinline__ int swzF(int e, int col)  { return (e * 512 + col) ^ ((e & 7) << 4); }
__device__ __forceinline__ int swz64(int r, int col) { return (r * 64 + col) ^ ((r & 7) << 4); }

__device__ __forceinline__ void stage16(const char* g, char* l) {
    __builtin_amdgcn_global_load_lds((const __attribute__((address_space(1))) u32*)g,
                                     (__attribute__((address_space(3))) u32*)l, 16, 0, 0);
}
__device__ __forceinline__ void split8(const float4& A, const float4& B, short8& h, short8& l) {
    const float v[8] = {A.x, A.y, A.z, A.w, B.x, B.y, B.z, B.w};
    #pragma unroll
    for (int j = 0; j < 8; ++j) {
        const u16 hh = f2bf(v[j]);
        h[j] = (short)hh;
        l[j] = (short)f2bf(v[j] - bf2f(hh));
    }
}
__device__ __forceinline__ void pacc(const float4& a, const float4& c, float& d, float& nu, float& nv) {
    d  = fmaf(a.x, c.x, d);  d  = fmaf(a.y, c.y, d);  d  = fmaf(a.z, c.z, d);  d  = fmaf(a.w, c.w, d);
    nu = fmaf(a.x, a.x, nu); nu = fmaf(a.y, a.y, nu); nu = fmaf(a.z, a.z, nu); nu = fmaf(a.w, a.w, nu);
    nv = fmaf(c.x, c.x, nv); nv = fmaf(c.y, c.y, nv); nv = fmaf(c.z, c.z, nv); nv = fmaf(c.w, c.w, nv);
}

// ---- prep: W1[k][m] -> per-chunk pre-swizzled LDS images (hi16KB|lo16KB) x 17 ----
__global__ void prep_w1t(const float* __restrict__ W1, u16* __restrict__ ws) {
    const int k = blockIdx.x;          // 0..543
    const int m = threadIdx.x;         // 0..255
    const float v = (k < 519) ? W1[k * 256 + m] : 0.0f;
    const u16 h = f2bf(v);
    const u16 l = f2bf(v - bf2f(h));
    const int kc = k >> 5, kl = k & 31;
    const int P = ((m * 64 + (kl >> 3) * 16) ^ ((m & 7) << 4)) + (kl & 7) * 2;
    u16* base = ws + (size_t)kc * (WCHUNK / 2);
    base[P / 2] = h;
    base[(16384 + P) / 2] = l;
}

__global__ __launch_bounds__(256)
void edge_mfma(const float* __restrict__ z,
               const int*   __restrict__ eidx,
               const float* __restrict__ extra,
               const float* __restrict__ b1,
               const float* __restrict__ W2,
               const float* __restrict__ b2,
               const u16*   __restrict__ ws,
               float* __restrict__ out)
{
    __shared__ alignas(16) char lds[LDS_SZ];
    const int t    = threadIdx.x;
    const int lane = t & 63;
    const int wv   = t >> 6;            // wave 0..3, owns cols [wv*64, wv*64+64)
    const int e0   = blockIdx.x * MTE;

    // prefetch W chunk 0 (linear image copy; per-wave 8KB = 8 x 1KB)
    {
        const char* src = (const char*)ws + (size_t)wv * 8192 + lane * 16;
        char* dst = lds + OFF_W + wv * 8192;           // wave-uniform; HW adds lane*16
        #pragma unroll
        for (int i = 0; i < 8; ++i) stage16(src + i * 1024, dst + i * 1024);
    }

    // edge indices (clamped for tail block)
    {
        int g = e0 + (t & 63);
        if (g >= NEDGES) g = NEDGES - 1;
        if (t < 64)       *(int*)(lds + OFF_SU + (t & 63) * 4) = eidx[g];
        else if (t < 128) *(int*)(lds + OFF_SV + (t & 63) * 4) = eidx[NEDGES + g];
    }
    __syncthreads();

    // ---- gather z_u/z_v, split to bf16 hi/lo into swizzled F, fused dot/cos ----
    {
        const int* su = (const int*)(lds + OFF_SU);
        const int* sv = (const int*)(lds + OFF_SV);
        #pragma unroll
        for (int r = 0; r < 2; ++r) {
            const int e   = wv * 8 + r * 32 + (lane & 7);
            const int oct = lane >> 3;                  // 16-k slice
            const float* pu = z + (size_t)su[e] * 128 + oct * 16;
            const float* pv = z + (size_t)sv[e] * 128 + oct * 16;
            const float4 a0 = *(const float4*)(pu + 0),  a1 = *(const float4*)(pu + 4);
            const float4 a2 = *(const float4*)(pu + 8),  a3 = *(const float4*)(pu + 12);
            const float4 c0 = *(const float4*)(pv + 0),  c1 = *(const float4*)(pv + 4);
            const float4 c2 = *(const float4*)(pv + 8),  c3 = *(const float4*)(pv + 12);
            float d = 0.f, nu = 0.f, nv = 0.f;
            pacc(a0, c0, d, nu, nv); pacc(a1, c1, d, nu, nv);
            pacc(a2, c2, d, nu, nv); pacc(a3, c3, d, nu, nv);
            short8 h8, l8;
            split8(a0, a1, h8, l8);
            *(short8*)(lds + OFF_FHI + swzF(e, oct * 32))        = h8;
            *(short8*)(lds + OFF_FLO + swzF(e, oct * 32))        = l8;
            split8(a2, a3, h8, l8);
            *(short8*)(lds + OFF_FHI + swzF(e, oct * 32 + 16))   = h8;
            *(short8*)(lds + OFF_FLO + swzF(e, oct * 32 + 16))   = l8;
            split8(c0, c1, h8, l8);
            *(short8*)(lds + OFF_FHI + swzF(e, 256 + oct * 32))      = h8;
            *(short8*)(lds + OFF_FLO + swzF(e, 256 + oct * 32))      = l8;
            split8(c2, c3, h8, l8);
            *(short8*)(lds + OFF_FHI + swzF(e, 256 + oct * 32 + 16)) = h8;
            *(short8*)(lds + OFF_FLO + swzF(e, 256 + oct * 32 + 16)) = l8;
            d  += __shfl_xor(d, 8);  d  += __shfl_xor(d, 16);  d  += __shfl_xor(d, 32);
            nu += __shfl_xor(nu, 8); nu += __shfl_xor(nu, 16); nu += __shfl_xor(nu, 32);
            nv += __shfl_xor(nv, 8); nv += __shfl_xor(nv, 16); nv += __shfl_xor(nv, 32);
            if ((lane >> 3) == 0) {
                *(float*)(lds + OFF_SDOT + e * 4) = d;
                const float nn = fmaxf(sqrtf(nu), 1e-12f) * fmaxf(sqrtf(nv), 1e-12f);
                *(float*)(lds + OFF_SCOS + e * 4) = d / nn;
            }
        }
    }
    __syncthreads();   // drains W-chunk-0 prefetch too (vmcnt 0 at barrier)

    const f32x4 vzero = {0.f, 0.f, 0.f, 0.f};
    f32x4 acc[4][4];
    #pragma unroll
    for (int mf = 0; mf < 4; ++mf)
        #pragma unroll
        for (int nf = 0; nf < 4; ++nf) acc[mf][nf] = vzero;

    const int el = lane & 15, kq = lane >> 4;

    // ---- K loop: 17 chunks; prefetch W(kc+1), build FC(kc+1), MFMA(kc), barrier ----
    for (int kc = 0; kc < NCH; ++kc) {
        if (kc < NCH - 1) {   // async W prefetch (drained by end-of-iter barrier)
            const char* src = (const char*)ws + (size_t)(kc + 1) * WCHUNK + wv * 8192 + lane * 16;
            char* dst = lds + OFF_W + ((kc + 1) & 1) * WCHUNK + wv * 8192;
            #pragma unroll
            for (int i = 0; i < 8; ++i) stage16(src + i * 1024, dst + i * 1024);
        }

        if (kc >= 7 && kc < 15) {   // build |diff| / prod chunk for kc+1
            const int kc1 = kc + 1;
            const int eL = (t & 15), kh = (t >> 4) & 3, eh = t >> 6;
            const int e = eh * 16 + eL;
            const int colu = (kc1 & 3) * 64 + kh * 16;
            const short8 uh = *(const short8*)(lds + OFF_FHI + swzF(e, colu));
            const short8 ul = *(const short8*)(lds + OFF_FLO + swzF(e, colu));
            const short8 vh = *(const short8*)(lds + OFF_FHI + swzF(e, 256 + colu));
            const short8 vl = *(const short8*)(lds + OFF_FLO + swzF(e, 256 + colu));
            const bool isabs = (kc1 < 12);
            short8 oh, ol;
            #pragma unroll
            for (int j = 0; j < 8; ++j) {
                const float u = bf2f((u16)uh[j]) + bf2f((u16)ul[j]);
                const float v = bf2f((u16)vh[j]) + bf2f((u16)vl[j]);
                const float x = isabs ? fabsf(u - v) : (u * v);
                const u16 hh = f2bf(x);
                oh[j] = (short)hh;
                ol[j] = (short)f2bf(x - bf2f(hh));
            }
            char* fcb = lds + OFF_FC + (kc1 & 1) * 8192;
            *(short8*)(fcb + swz64(e, kh * 16))        = oh;
            *(short8*)(fcb + 4096 + swz64(e, kh * 16)) = ol;
        } else if (kc == 15) {      // build tail chunk (dot, cos, extra, zero-pad)
            if (t < 64) {
                const int e = t;
                int g = e0 + e; if (g >= NEDGES) g = NEDGES - 1;
                float vals[8];
                vals[0] = *(const float*)(lds + OFF_SDOT + e * 4);
                vals[1] = *(const float*)(lds + OFF_SCOS + e * 4);
                #pragma unroll
                for (int j = 0; j < 5; ++j) vals[2 + j] = extra[(size_t)g * 5 + j];
                vals[7] = 0.0f;
                short8 oh, ol;
                #pragma unroll
                for (int j = 0; j < 8; ++j) {
                    const u16 hh = f2bf(vals[j]);
                    oh[j] = (short)hh;
                    ol[j] = (short)f2bf(vals[j] - bf2f(hh));
                }
                char* fcb = lds + OFF_FC;              // chunk 16 -> buf 0
                *(short8*)(fcb + swz64(e, 0))        = oh;
                *(short8*)(fcb + 4096 + swz64(e, 0)) = ol;
                const short8 zz = {0,0,0,0,0,0,0,0};
                #pragma unroll
                for (int c = 16; c < 64; c += 16) {
                    *(short8*)(fcb + swz64(e, c))        = zz;
                    *(short8*)(fcb + 4096 + swz64(e, c)) = zz;
                }
            }
        }

        // ---- MFMA phase: 48 mfma_16x16x32_bf16 per wave ----
        short8 Bh[4], Bl[4];
        if (kc < 8) {
            const int colb = kc * 64 + kq * 16;
            #pragma unroll
            for (int nf = 0; nf < 4; ++nf) {
                const int off = swzF(nf * 16 + el, colb);
                Bh[nf] = *(const short8*)(lds + OFF_FHI + off);
                Bl[nf] = *(const short8*)(lds + OFF_FLO + off);
            }
        } else {
            const char* fcb = lds + OFF_FC + (kc & 1) * 8192;
            #pragma unroll
            for (int nf = 0; nf < 4; ++nf) {
                const int off = swz64(nf * 16 + el, kq * 16);
                Bh[nf] = *(const short8*)(fcb + off);
                Bl[nf] = *(const short8*)(fcb + 4096 + off);
            }
        }
        const char* wb = lds + OFF_W + (kc & 1) * WCHUNK;
        #pragma unroll
        for (int mf = 0; mf < 4; ++mf) {
            const int offA = swz64(wv * 64 + mf * 16 + el, kq * 16);
            const short8 Ah = *(const short8*)(wb + offA);
            const short8 Al = *(const short8*)(wb + 16384 + offA);
            #pragma unroll
            for (int nf = 0; nf < 4; ++nf) {
                acc[mf][nf] = __builtin_amdgcn_mfma_f32_16x16x32_bf16(Ah, Bh[nf], acc[mf][nf], 0, 0, 0);
                acc[mf][nf] = __builtin_amdgcn_mfma_f32_16x16x32_bf16(Al, Bh[nf], acc[mf][nf], 0, 0, 0);
                acc[mf][nf] = __builtin_amdgcn_mfma_f32_16x16x32_bf16(Ah, Bl[nf], acc[mf][nf], 0, 0, 0);
            }
        }
        __syncthreads();   // orders FC/W buffers; drains the 1-ahead W prefetch
    }

    // ---- epilogue: bias+ReLU, GEMM2 (256->2) reduce, softplus ----
    // D mapping: m = wv*64 + mf*16 + kq*4 + r ; e = nf*16 + el
    float b1r[4][4], w20[4][4], w21[4][4];
    #pragma unroll
    for (int mf = 0; mf < 4; ++mf) {
        const int mb = wv * 64 + mf * 16 + kq * 4;
        const float4 bv = *(const float4*)&b1[mb];
        b1r[mf][0] = bv.x; b1r[mf][1] = bv.y; b1r[mf][2] = bv.z; b1r[mf][3] = bv.w;
        #pragma unroll
        for (int r = 0; r < 4; ++r) {
            w20[mf][r] = W2[2 * (mb + r)];
            w21[mf][r] = W2[2 * (mb + r) + 1];
        }
    }
    #pragma unroll
    for (int nf = 0; nf < 4; ++nf) {
        float p0 = 0.f, p1 = 0.f;
        #pragma unroll
        for (int mf = 0; mf < 4; ++mf)
            #pragma unroll
            for (int r = 0; r < 4; ++r) {
                const float h = fmaxf(acc[mf][nf][r] + b1r[mf][r], 0.0f);
                p0 = fmaf(h, w20[mf][r], p0);
                p1 = fmaf(h, w21[mf][r], p1);
            }
        p0 += __shfl_xor(p0, 16); p0 += __shfl_xor(p0, 32);
        p1 += __shfl_xor(p1, 16); p1 += __shfl_xor(p1, 32);
        if (kq == 0)
            *(float2*)(lds + OFF_SRED + (wv * 64 + nf * 16 + el) * 8) = make_float2(p0, p1);
    }
    __syncthreads();
    if (t < 64) {
        float s0 = b2[0], s1 = b2[1];
        #pragma unroll
        for (int w = 0; w < 4; ++w) {
            const float2 pr = *(const float2*)(lds + OFF_SRED + (w * 64 + t) * 8);
            s0 += pr.x; s1 += pr.y;
        }
        const int g = e0 + t;
        if (g < NEDGES) {
            out[2 * (size_t)g + 0] = softplus_f(s0);
            out[2 * (size_t)g + 1] = softplus_f(s1);
        }
    }
}

extern "C" void kernel_launch(void* const* d_in, const int* in_sizes, int n_in,
                              void* d_out, int out_size, void* d_ws, size_t ws_size,
                              hipStream_t stream) {
    const float* zp    = (const float*)d_in[0];
    const int*   eidx  = (const int*)  d_in[1];
    const float* extra = (const float*)d_in[2];
    const float* W1    = (const float*)d_in[3];
    const float* b1    = (const float*)d_in[4];
    const float* W2    = (const float*)d_in[5];
    const float* b2    = (const float*)d_in[6];
    float* out = (float*)d_out;
    u16* ws = (u16*)d_ws;   // needs 17*32768 = 557056 B (ws re-written every launch)

    prep_w1t<<<dim3(NCH * 32), dim3(256), 0, stream>>>(W1, ws);   // 544 k-rows
    edge_mfma<<<dim3(NBLK), dim3(256), 0, stream>>>(zp, eidx, extra, b1, W2, b2, ws, out);
}